// Round 11
// baseline (221.223 us; speedup 1.0000x reference)
//
#include <hip/hip_runtime.h>
#include <math.h>

#define F_IN 128
#define NHD 8
#define FEAT 128   // NHD*FO
#define NEG_SLOPE 0.2f
#define LN_EPS 1e-5f
#define BSH 7      // 128 nodes per bucket
#define BMSK 127
#define NPQ 16     // nodes per k_ba block (1/8 bucket)
#define CAP 48     // per-node slot capacity in LDS; deg>CAP -> fallback
#define EPB 2048   // edges sorted per phase-A block (512 thr x 4)
#define NBMAX 512  // max buckets (n <= 65536)
#define GROWS 64   // GEMM rows per block

typedef __bf16 v8bf __attribute__((ext_vector_type(8)));
typedef __bf16 v2bf __attribute__((ext_vector_type(2)));
typedef float f32x4 __attribute__((ext_vector_type(4)));

// transpose + cast W: WT[c][k] = bf16(W[k][c])
__global__ __launch_bounds__(256) void k_wt(const float* __restrict__ W,
                                            __bf16* __restrict__ WT) {
    int idx = blockIdx.x * 256 + threadIdx.x;   // 16384 total
    int k = idx >> 7, c = idx & 127;
    WT[c * 128 + k] = (__bf16)W[idx];
}

// Fused: blocks [0,Ga) = block-local counting sort of 2048 edges by dst
// bucket (no global atomics, coalesced output); blocks [Ga,..) = MFMA GEMM
// (64 rows, LDS-staged input AND output -> coalesced stores, LDS att dots).
__global__ __launch_bounds__(512) void k_fused(const float* __restrict__ x,
                                               const __bf16* __restrict__ WT,
                                               const float* __restrict__ att_src,
                                               const float* __restrict__ att_dst,
                                               __bf16* __restrict__ xp16,
                                               float* __restrict__ a_src,
                                               float* __restrict__ a_dst,
                                               const int* __restrict__ src,
                                               const int* __restrict__ dst,
                                               unsigned int* __restrict__ sorted_g,
                                               int* __restrict__ runptr,
                                               int n, int E, int Ga) {
    extern __shared__ char smem[];
    if ((int)blockIdx.x < Ga) {
        // ---- phase A: block-local counting sort ----
        int* lcnt = (int*)smem;                          // 512
        int* loff = lcnt + NBMAX;                        // 513
        unsigned int* sorted_l = (unsigned int*)(loff + NBMAX + 1);  // 2048
        int* wtot = (int*)(sorted_l + EPB);              // 8
        int* wexcl = wtot + 8;                           // 8
        int NB = (n + BMSK) >> BSH;
        int tid = threadIdx.x, lane = tid & 63, wid = tid >> 6;
        long base0 = (long)blockIdx.x * EPB;
        long total = (long)E + n;
        if (tid < NB) lcnt[tid] = 0;
        __syncthreads();

        int s0[4], d0[4];
        bool val[4];
        long e0 = base0 + (long)tid * 4;
        if (e0 + 3 < E) {
            int4 sv = *(const int4*)(src + e0);
            int4 dv = *(const int4*)(dst + e0);
            s0[0] = sv.x; s0[1] = sv.y; s0[2] = sv.z; s0[3] = sv.w;
            d0[0] = dv.x; d0[1] = dv.y; d0[2] = dv.z; d0[3] = dv.w;
            val[0] = val[1] = val[2] = val[3] = true;
        } else {
#pragma unroll
            for (int j = 0; j < 4; ++j) {
                long e = e0 + j;
                val[j] = (e < total);
                s0[j] = d0[j] = 0;
                if (val[j]) {
                    if (e < E) { s0[j] = src[e]; d0[j] = dst[e]; }
                    else { s0[j] = d0[j] = (int)(e - E); }
                }
            }
        }
#pragma unroll
        for (int j = 0; j < 4; ++j)
            if (val[j]) atomicAdd(&lcnt[d0[j] >> BSH], 1);
        __syncthreads();

        // exclusive scan of lcnt[0..NB)
        int v = (tid < NB) ? lcnt[tid] : 0;
        int xx = v;
#pragma unroll
        for (int o = 1; o < 64; o <<= 1) {
            int t2 = __shfl_up(xx, o);
            if (lane >= o) xx += t2;
        }
        if (lane == 63) wtot[wid] = xx;
        __syncthreads();
        if (wid == 0 && lane < 8) {
            int s = wtot[lane];
            int y = s;
#pragma unroll
            for (int o = 1; o < 8; o <<= 1) {
                int t2 = __shfl_up(y, o);
                if (lane >= o) y += t2;
            }
            wexcl[lane] = y - s;
        }
        __syncthreads();
        int excl = wexcl[wid] + xx - v;
        if (tid < NB) loff[tid] = excl;
        if (tid == NB - 1) loff[NB] = excl + v;
        __syncthreads();
        if (tid < NB) lcnt[tid] = loff[tid];   // cursor
        __syncthreads();
#pragma unroll
        for (int j = 0; j < 4; ++j) {
            if (val[j]) {
                int b = d0[j] >> BSH;
                int pos = atomicAdd(&lcnt[b], 1);
                sorted_l[pos] = ((unsigned)s0[j] << BSH) | (unsigned)(d0[j] & BMSK);
            }
        }
        __syncthreads();
        int tv = loff[NB];
        for (int i = tid; i < tv; i += 512)
            sorted_g[base0 + i] = sorted_l[i];
        if (tid <= NB) runptr[(long)blockIdx.x * (NBMAX + 1) + tid] = loff[tid];
    } else {
        // ---- GEMM path: 64 rows staged to LDS; 8 waves = 8 heads, 4 tiles
        //      each; results staged to LDS -> coalesced stores + att dots ----
        __bf16* xs = (__bf16*)smem;            // 64 x 136
        __bf16* ys = xs + GROWS * 136;         // 64 x 136
        int gb = blockIdx.x - Ga;
        int tid = threadIdx.x;
        int rowbase = gb * GROWS;
#pragma unroll
        for (int rep = 0; rep < 4; ++rep) {
            int i4 = tid + rep * 512;          // 2048 float4
            int r = i4 >> 5, c4 = i4 & 31;
            int gr = rowbase + r; if (gr > n - 1) gr = n - 1;
            float4 xv = *(const float4*)(x + (long)gr * 128 + c4 * 4);
            __bf16* p = xs + r * 136 + c4 * 4;
            p[0] = (__bf16)xv.x; p[1] = (__bf16)xv.y;
            p[2] = (__bf16)xv.z; p[3] = (__bf16)xv.w;
        }
        __syncthreads();
        int wv = tid >> 6, lane = tid & 63;
        int m = lane & 15, quad = lane >> 4;
        int colbase = wv * 16;
        const __bf16* wcol = WT + (colbase + m) * 128;
        v8bf wf[4];
#pragma unroll
        for (int kk = 0; kk < 4; ++kk)
            wf[kk] = *(const v8bf*)(wcol + kk * 32 + quad * 8);
#pragma unroll
        for (int t = 0; t < 4; ++t) {
            int rb = t * 16;
            f32x4 acc = {0.f, 0.f, 0.f, 0.f};
#pragma unroll
            for (int kk = 0; kk < 4; ++kk) {
                v8bf a = *(const v8bf*)(xs + (rb + m) * 136 + kk * 32 + quad * 8);
                acc = __builtin_amdgcn_mfma_f32_16x16x32_bf16(a, wf[kk], acc, 0, 0, 0);
            }
#pragma unroll
            for (int r = 0; r < 4; ++r)
                ys[(rb + quad * 4 + r) * 136 + colbase + m] = (__bf16)acc[r];
        }
        __syncthreads();
        // coalesced xp16 store: 64 rows x 256 B
#pragma unroll
        for (int rep = 0; rep < 2; ++rep) {
            int i8 = tid + rep * 512;          // 1024 chunks of 16 B
            int r = i8 >> 4, c8 = i8 & 15;
            int gr = rowbase + r;
            if (gr < n)
                *(v8bf*)(xp16 + (long)gr * 128 + c8 * 8) = *(v8bf*)(ys + r * 136 + c8 * 8);
        }
        // att dots: thread t = (row, head); 2 ds_read_b128 + 32 fma
        {
            int r = tid >> 3, h = tid & 7;
            int gr = rowbase + r;
            if (gr < n) {
                const __bf16* yr = ys + r * 136 + h * 16;
                v8bf y0 = *(const v8bf*)yr;
                v8bf y1 = *(const v8bf*)(yr + 8);
                const float* as = att_src + h * 16;
                const float* ad = att_dst + h * 16;
                float ts = 0.f, td = 0.f;
#pragma unroll
                for (int k = 0; k < 8; ++k) {
                    float v0 = (float)y0[k], v1 = (float)y1[k];
                    ts += v0 * as[k] + v1 * as[k + 8];
                    td += v0 * ad[k] + v1 * ad[k + 8];
                }
                a_src[gr * 8 + h] = ts;
                a_dst[gr * 8 + h] = td;
            }
        }
    }
}

// 8 blocks per 128-node bucket (16 nodes each): gather this slice's entries
// from all phase-A runs into LDS slot lists, then wave-per-node register
// aggregation (batched weight gather -> deep MLP) + LayerNorm + store.
__global__ __launch_bounds__(256) void k_ba(const unsigned int* __restrict__ sorted_g,
                                            const int* __restrict__ runptr,
                                            const float* __restrict__ a_src,
                                            const float* __restrict__ a_dst,
                                            const __bf16* __restrict__ xp16,
                                            const float* __restrict__ bias,
                                            const float* __restrict__ gamma,
                                            const float* __restrict__ beta,
                                            const int* __restrict__ src,
                                            const int* __restrict__ dst,
                                            float* __restrict__ out, int n, int E, int Ga) {
    __shared__ int slds[NPQ * CAP];       // 3 KB slot lists
    __shared__ int lc[NPQ];
    __shared__ float adst_s[NPQ * NHD];   // 0.5 KB
    int b = blockIdx.x >> 3;
    int q = blockIdx.x & 7;
    int tid = threadIdx.x;
    int node0 = (b << BSH) + q * NPQ;
    if (tid < NPQ) lc[tid] = 0;
    if (tid < NPQ * NHD) {
        int nd = node0 + (tid >> 3);
        adst_s[tid] = (nd < n) ? a_dst[nd * NHD + (tid & 7)] : 0.f;
    }
    __syncthreads();

    // ---- build: one thread per phase-A run; filter to this 16-node slice ----
    int qlo = q * NPQ;
    for (int blk = tid; blk < Ga; blk += 256) {
        const int* rp = runptr + (long)blk * (NBMAX + 1) + b;
        int st = rp[0], en = rp[1];
        const unsigned int* sg = sorted_g + (long)blk * EPB;
        for (int i = st; i < en; ++i) {
            unsigned int u = sg[i];
            int dl = (int)(u & BMSK) - qlo;
            if ((unsigned)dl < NPQ) {
                int p = atomicAdd(&lc[dl], 1);
                if (p < CAP) slds[dl * CAP + p] = (int)(u >> BSH);
            }
        }
    }
    __syncthreads();
    // pad each list to a multiple of 8 with dummy id 0 (weight forced to 0)
    if (tid < NPQ) {
        int cc = lc[tid]; if (cc > CAP) cc = CAP;
        int pad = (cc + 7) & ~7; if (pad > CAP) pad = CAP;
        for (int p = cc; p < pad; ++p) slds[tid * CAP + p] = 0;
    }
    __syncthreads();

    int lane = tid & 63, wv = tid >> 6;
    int h = lane & 7, j8 = lane >> 3;
    float2 bs = *(const float2*)(bias + 2 * lane);
    float2 g  = *(const float2*)(gamma + 2 * lane);
    float2 bt = *(const float2*)(beta + 2 * lane);

    // ---- aggregate: wave wv handles nodes wv, wv+4, ... ----
    for (int i = wv; i < NPQ; i += 4) {
        int node = node0 + i;
        if (node >= n) break;
        int cnt = lc[i];
        float acc0 = 0.f, acc1 = 0.f, inv;

        if (cnt <= CAP) {
            const int* row = slds + i * CAP;
            float b_h = adst_s[i * NHD + h];
            int C = (cnt + 7) >> 3;            // chunks, <= 6
            // phase W: batched weight gather (all chunks' loads in flight)
            int smy[6]; float av[6], w_all[6];
#pragma unroll
            for (int c = 0; c < 6; ++c) if (c < C) smy[c] = row[c * 8 + j8];
#pragma unroll
            for (int c = 0; c < 6; ++c) if (c < C) av[c] = a_src[smy[c] * NHD + h];
            float zacc = 0.f;
#pragma unroll
            for (int c = 0; c < 6; ++c) if (c < C) {
                float e = av[c] + b_h;
                e = e > 0.f ? e : NEG_SLOPE * e;
                float w = (c * 8 + j8 < cnt) ? __expf(e) : 0.f;
                w_all[c] = w;
                zacc += w;
            }
            zacc += __shfl_xor(zacc, 8);
            zacc += __shfl_xor(zacc, 16);
            zacc += __shfl_xor(zacc, 32);
            float z = __shfl(zacc, j8);
            inv = 1.f / z;
            // phase F: feature gather; weights are ready registers
#pragma unroll
            for (int c = 0; c < 6; ++c) if (c < C) {
                int base = c * 8;
                int ss[8];
#pragma unroll
                for (int j = 0; j < 8; ++j) ss[j] = row[base + j];
                float2 vals[8];
#pragma unroll
                for (int j = 0; j < 8; ++j) {
                    v2bf p = *(const v2bf*)(xp16 + (long)ss[j] * FEAT + 2 * lane);
                    vals[j] = make_float2((float)p[0], (float)p[1]);
                }
#pragma unroll
                for (int j = 0; j < 8; ++j) {
                    float w = __shfl(w_all[c], j * 8 + j8);
                    acc0 = fmaf(w, vals[j].x, acc0);
                    acc1 = fmaf(w, vals[j].y, acc1);
                }
            }
        } else {
            // ---- fallback (deg > CAP; never expected): rescan edge list ----
            float b_h = a_dst[node * NHD + j8];
            float z = 0.f;
            {   // self-loop
                float e = a_src[node * NHD + j8] + b_h;
                e = e > 0.f ? e : NEG_SLOPE * e;
                float w = __expf(e);
                z += w;
                v2bf p = *(const v2bf*)(xp16 + (long)node * FEAT + 2 * lane);
                acc0 = fmaf(w, (float)p[0], acc0);
                acc1 = fmaf(w, (float)p[1], acc1);
            }
            for (int base = 0; base < E; base += 64) {
                int e = base + lane;
                int sv = 0;
                bool mt = false;
                if (e < E) { mt = (dst[e] == node); if (mt) sv = src[e]; }
                unsigned long long mask = __ballot(mt);
                while (mask) {
                    int bl = __ffsll(mask) - 1;
                    mask &= mask - 1;
                    int s = __shfl(sv, bl);
                    float ee = a_src[s * NHD + j8] + b_h;
                    ee = ee > 0.f ? ee : NEG_SLOPE * ee;
                    float w = __expf(ee);
                    z += w;
                    v2bf p = *(const v2bf*)(xp16 + (long)s * FEAT + 2 * lane);
                    acc0 = fmaf(w, (float)p[0], acc0);
                    acc1 = fmaf(w, (float)p[1], acc1);
                }
            }
            inv = 1.f / z;
        }

        // ---- epilogue: normalize, bias, LayerNorm, store ----
        float v0 = acc0 * inv + bs.x;
        float v1 = acc1 * inv + bs.y;
        float ssum = v0 + v1;
        float ssq = v0 * v0 + v1 * v1;
#pragma unroll
        for (int o = 32; o > 0; o >>= 1) {
            ssum += __shfl_xor(ssum, o);
            ssq += __shfl_xor(ssq, o);
        }
        float mu = ssum * (1.0f / FEAT);
        float var = ssq * (1.0f / FEAT) - mu * mu;
        float rs = rsqrtf(var + LN_EPS);
        float2 o2;
        o2.x = (v0 - mu) * rs * g.x + bt.x;
        o2.y = (v1 - mu) * rs * g.y + bt.y;
        *(float2*)(out + (long)node * FEAT + 2 * lane) = o2;
    }
}

extern "C" void kernel_launch(void* const* d_in, const int* in_sizes, int n_in,
                              void* d_out, int out_size, void* d_ws, size_t ws_size,
                              hipStream_t stream) {
    const float* x = (const float*)d_in[0];
    const int* edge_index = (const int*)d_in[1];
    const float* W = (const float*)d_in[2];
    const float* att_src = (const float*)d_in[3];
    const float* att_dst = (const float*)d_in[4];
    const float* bias = (const float*)d_in[5];
    const float* gamma = (const float*)d_in[6];
    const float* beta = (const float*)d_in[7];
    float* out = (float*)d_out;

    int n = in_sizes[0] / F_IN;
    int E = in_sizes[1] / 2;
    const int* src = edge_index;
    const int* dst = edge_index + E;
    int NB = (n + BMSK) >> BSH;
    int Ga = (E + n + EPB - 1) / EPB;

    char* ws = (char*)d_ws;
    __bf16* WT   = (__bf16*)ws;                    ws += (size_t)128 * 128 * 2;
    __bf16* xp16 = (__bf16*)ws;                    ws += (size_t)n * FEAT * 2;
    float* a_src = (float*)ws;                     ws += (size_t)n * NHD * 4;
    float* a_dst = (float*)ws;                     ws += (size_t)n * NHD * 4;
    unsigned int* sorted_g = (unsigned int*)ws;    ws += (size_t)Ga * EPB * 4;
    int* runptr  = (int*)ws;                       ws += (size_t)Ga * (NBMAX + 1) * 4;

    k_wt<<<64, 256, 0, stream>>>(W, WT);
    int Gg = (n + GROWS - 1) / GROWS;
    size_t smem = (size_t)GROWS * 136 * 2 * 2;     // xs + ys (34.8 KB)
    k_fused<<<Ga + Gg, 512, smem, stream>>>(x, WT, att_src, att_dst, xp16, a_src, a_dst,
                                            src, dst, sorted_g, runptr, n, E, Ga);
    k_ba<<<NB * 8, 256, 0, stream>>>(sorted_g, runptr, a_src, a_dst, xp16,
                                     bias, gamma, beta, src, dst, out, n, E, Ga);
}